// Round 4
// baseline (184.798 us; speedup 1.0000x reference)
//
#include <hip/hip_runtime.h>
#include <hip/hip_bf16.h>
#include <hip/hip_cooperative_groups.h>
#include <stdint.h>

namespace cg = cooperative_groups;

#define BB 2
#define SS 2048
#define DD 512
#define PP 13
#define TT 5
#define MH 64
#define MM (BB*SS)      // 4096 rows
#define NV (TT*DD)      // 2560
#define KK 512
#define CHUNK 16
#define NCH (SS/CHUNK)  // 128

typedef __attribute__((ext_vector_type(4))) float f32x4;
typedef __attribute__((ext_vector_type(8))) short s8v;
typedef unsigned int u32;
typedef __attribute__((address_space(3))) u32 lds_u32_t;
typedef __attribute__((address_space(1))) const u32 glb_u32_t;

__device__ __forceinline__ float bf2f(unsigned short u){
  union { unsigned int i; float f; } c; c.i = ((unsigned int)u) << 16; return c.f;
}
__device__ __forceinline__ unsigned short f2bf(float f){
  union { float f; unsigned int i; } c; c.f = f;
  unsigned int x = c.i;
  unsigned int r = (x + 0x7fffu + ((x >> 16) & 1u)) >> 16;
  return (unsigned short)r;
}
// async global->LDS, 16B per lane; LDS dest is wave-uniform base + lane*16
__device__ __forceinline__ void gld16(unsigned short* l, const unsigned short* g){
  __builtin_amdgcn_global_load_lds((glb_u32_t*)g, (lds_u32_t*)l, 16, 0, 0);
}

// ---------------------------------------------------------------- merged LN + weight-prep
// blocks [0,1024): LayerNorm, 4 rows each
// blocks [1024,1152): W_vT = mix-contracted W_in (transposed bf16) + b_v
// blocks [1152,1280): W_outT bf16
// blocks [1280,1296): W1T bf16
__global__ __launch_bounds__(256) void k_prep_ln(
    const float* __restrict__ hs,
    const float* __restrict__ gamma, const float* __restrict__ beta,
    const float* __restrict__ W_in, const float* __restrict__ b_in,
    const float* __restrict__ mix,  const float* __restrict__ W_out,
    const float* __restrict__ W1,
    unsigned short* __restrict__ xn_bf,
    unsigned short* __restrict__ W_vT, float* __restrict__ b_v,
    unsigned short* __restrict__ W_outT, unsigned short* __restrict__ W1T)
{
  int blk = blockIdx.x;
  if (blk < 1024){
    int tid = threadIdx.x;
    int lane = tid & 63;
    int row = blk*4 + (tid>>6);
    const float* x = hs + (size_t)row*DD + lane*8;
    float4 v0 = *(const float4*)x;
    float4 v1 = *(const float4*)(x+4);
    float s  = v0.x+v0.y+v0.z+v0.w + v1.x+v1.y+v1.z+v1.w;
    float sq = v0.x*v0.x+v0.y*v0.y+v0.z*v0.z+v0.w*v0.w
             + v1.x*v1.x+v1.y*v1.y+v1.z*v1.z+v1.w*v1.w;
    #pragma unroll
    for (int o=32;o>0;o>>=1){ s += __shfl_xor(s,o); sq += __shfl_xor(sq,o); }
    float mu   = s  * (1.f/DD);
    float var  = sq * (1.f/DD) - mu*mu;
    float rstd = rsqrtf(var + 1e-5f);
    float4 g0 = *(const float4*)(gamma + lane*8);
    float4 g1 = *(const float4*)(gamma + lane*8 + 4);
    float4 b0 = *(const float4*)(beta  + lane*8);
    float4 b1 = *(const float4*)(beta  + lane*8 + 4);
    union { unsigned short us[8]; uint4 u; } pk;
    pk.us[0] = f2bf((v0.x-mu)*rstd*g0.x + b0.x);
    pk.us[1] = f2bf((v0.y-mu)*rstd*g0.y + b0.y);
    pk.us[2] = f2bf((v0.z-mu)*rstd*g0.z + b0.z);
    pk.us[3] = f2bf((v0.w-mu)*rstd*g0.w + b0.w);
    pk.us[4] = f2bf((v1.x-mu)*rstd*g1.x + b1.x);
    pk.us[5] = f2bf((v1.y-mu)*rstd*g1.y + b1.y);
    pk.us[6] = f2bf((v1.z-mu)*rstd*g1.z + b1.z);
    pk.us[7] = f2bf((v1.w-mu)*rstd*g1.w + b1.w);
    *(uint4*)(xn_bf + (size_t)row*DD + lane*8) = pk.u;
  } else if (blk < 1152){
    int idx = (blk-1024) * 256 + threadIdx.x;   // 32768 total
    int d  = idx & (DD-1);
    int k0 = idx >> 9;                   // 0..63 (8 k's each)
    float mx[PP][TT];
    #pragma unroll
    for (int p=0;p<PP;++p)
      #pragma unroll
      for (int t=0;t<TT;++t) mx[p][t] = mix[p*TT+t];
    float acc[TT][8];
    #pragma unroll
    for (int t=0;t<TT;++t)
      #pragma unroll
      for (int j=0;j<8;++j) acc[t][j] = 0.f;
    #pragma unroll
    for (int j=0;j<8;++j){
      int k = k0*8 + j;
      const float* wrow = W_in + (size_t)k * (PP*DD) + d;
      #pragma unroll
      for (int p=0;p<PP;++p){
        float w = wrow[p*DD];
        #pragma unroll
        for (int t=0;t<TT;++t) acc[t][j] += mx[p][t]*w;
      }
    }
    #pragma unroll
    for (int t=0;t<TT;++t){
      union { unsigned short us[8]; uint4 u; } pk;
      #pragma unroll
      for (int j=0;j<8;++j) pk.us[j] = f2bf(acc[t][j]);
      *(uint4*)(W_vT + ((size_t)(t*DD+d))*KK + k0*8) = pk.u;
    }
    if (k0 == 0){
      #pragma unroll
      for (int t=0;t<TT;++t){
        float s = 0.f;
        #pragma unroll
        for (int p=0;p<PP;++p) s += mx[p][t]*b_in[p*DD+d];
        b_v[t*DD+d] = s;
      }
    }
  } else if (blk < 1280){
    int idx = (blk-1152)*256 + threadIdx.x; // 32768
    int n  = idx & (DD-1);
    int k0 = idx >> 9;
    union { unsigned short us[8]; uint4 u; } pk;
    #pragma unroll
    for (int j=0;j<8;++j) pk.us[j] = f2bf(W_out[(size_t)(k0*8+j)*DD + n]);
    *(uint4*)(W_outT + (size_t)n*KK + k0*8) = pk.u;
  } else {
    int idx = (blk-1280)*256 + threadIdx.x; // 4096
    int n  = idx >> 6;       // 0..63
    int k0 = idx & 63;       // 8 k's each
    union { unsigned short us[8]; uint4 u; } pk;
    #pragma unroll
    for (int j=0;j<8;++j) pk.us[j] = f2bf(W1[(size_t)(k0*8+j)*MH + n]);
    *(uint4*)(W1T + (size_t)n*KK + k0*8) = pk.u;
  }
}

// ---------------------------------------------------------------- gate: z1=tanh(xn@W1), z2=z1@W2+b2, alpha=exp(-sigmoid(z2)/tau)
__global__ __launch_bounds__(256) void k_gate(
    const unsigned short* __restrict__ xn,
    const unsigned short* __restrict__ W1T,
    const float* __restrict__ b1, const float* __restrict__ W2,
    const float* __restrict__ b2, const float* __restrict__ ltau,
    float* __restrict__ alpha)
{
  __shared__ unsigned short lA[2][64*32];
  __shared__ unsigned short lB[2][64*32];
  int bm = blockIdx.x;
  int tid = threadIdx.x, lane = tid & 63, w = tid >> 6;
  int lr = lane & 15, kq = lane >> 4;
  const uint8_t* gA = (const uint8_t*)(xn  + (size_t)(bm*64 + w*16 + (lane>>2))*KK) + (lane&3)*16;
  const uint8_t* gB = (const uint8_t*)(W1T + (size_t)(        w*16 + (lane>>2))*KK) + (lane&3)*16;
  f32x4 acc[4];
  #pragma unroll
  for (int ni=0;ni<4;++ni) acc[ni] = (f32x4){0.f,0.f,0.f,0.f};

  auto stage = [&](int buf, int kt){
    int off = kt*64;  // bytes
    gld16(&lA[buf][(w*16)*32], (const unsigned short*)(gA + off));
    gld16(&lB[buf][(w*16)*32], (const unsigned short*)(gB + off));
  };
  auto compute = [&](int buf){
    union { uint4 u; s8v v; } af, bfr[4];
    af.u = *(const uint4*)&lA[buf][(w*16+lr)*32 + kq*8];
    #pragma unroll
    for (int ni=0;ni<4;++ni) bfr[ni].u = *(const uint4*)&lB[buf][(ni*16+lr)*32 + kq*8];
    #pragma unroll
    for (int ni=0;ni<4;++ni)
      acc[ni] = __builtin_amdgcn_mfma_f32_16x16x32_bf16(af.v, bfr[ni].v, acc[ni], 0,0,0);
  };

  stage(0, 0);
  __syncthreads();
  #pragma unroll
  for (int kt=1; kt<16; ++kt){
    stage(kt&1, kt);
    compute((kt&1)^1);
    __syncthreads();
  }
  compute(1);

  float z1[4][4];
  #pragma unroll
  for (int ni=0;ni<4;++ni){
    float bb = b1[ni*16+lr];
    #pragma unroll
    for (int r=0;r<4;++r) z1[r][ni] = tanhf(acc[ni][r] + bb);
  }
  float et[TT];
  #pragma unroll
  for (int t=0;t<TT;++t) et[t] = expf(-ltau[t]);
  float a[4][TT];
  #pragma unroll
  for (int t=0;t<TT;++t){
    float w2[4];
    #pragma unroll
    for (int ni=0;ni<4;++ni) w2[ni] = W2[(ni*16+lr)*TT + t];
    #pragma unroll
    for (int r=0;r<4;++r){
      float p = z1[r][0]*w2[0] + z1[r][1]*w2[1] + z1[r][2]*w2[2] + z1[r][3]*w2[3];
      #pragma unroll
      for (int o=8;o>0;o>>=1) p += __shfl_xor(p, o);
      float z2 = p + b2[t];
      float gate = 1.f/(1.f + expf(-z2));
      a[r][t] = expf(-gate * et[t]);
    }
  }
  if (lr < TT){
    int t = lr;
    #pragma unroll
    for (int r=0;r<4;++r){
      int row = bm*64 + w*16 + kq*4 + r;
      alpha[(size_t)row*TT + t] = a[r][t];
    }
  }
}

// ---------------------------------------------------------------- bf16 MFMA GEMM, 2-phase dbuf: C = A(M,K)*Bt(N,K)^T (+bias)[+epilogue]
template<int BN, int NDIM, bool OUTEPI>
__global__ __launch_bounds__(256) void k_gemm(
    const unsigned short* __restrict__ A,
    const unsigned short* __restrict__ Bt,
    const float* __restrict__ bias,
    const float* __restrict__ hidden,
    const float* __restrict__ scale_p,
    float* __restrict__ outF,
    unsigned short* __restrict__ outBf)
{
  constexpr int NI  = (BN == 128) ? 4 : 2;
  constexpr int WNT = BN / 2;
  __shared__ unsigned short lA[2][128*32];
  __shared__ unsigned short lB[2][BN*32];
  int bn = blockIdx.x, bm = blockIdx.y;
  int tid  = threadIdx.x;
  int lane = tid & 63;
  int w    = tid >> 6;
  int wm = w >> 1, wn = w & 1;
  f32x4 acc[4][NI];
  #pragma unroll
  for (int i=0;i<4;++i)
    #pragma unroll
    for (int j=0;j<NI;++j) acc[i][j] = (f32x4){0.f,0.f,0.f,0.f};

  const uint8_t* gA = (const uint8_t*)(A + (size_t)(bm*128 + w*32 + (lane>>2))*KK) + (lane&3)*16;
  const uint8_t* gB;
  if constexpr (BN == 128) gB = (const uint8_t*)(Bt + (size_t)(bn*BN + w*32 + (lane>>2))*KK) + (lane&3)*16;
  else                     gB = (const uint8_t*)(Bt + (size_t)(bn*BN + w*16 + (lane>>2))*KK) + (lane&3)*16;
  int lr = lane & 15, kq = lane >> 4;

  auto stage = [&](int buf, int kt){
    int off = kt*64;  // bytes
    gld16(&lA[buf][(w*32)*32],    (const unsigned short*)(gA + off));
    gld16(&lA[buf][(w*32+16)*32], (const unsigned short*)(gA + (size_t)16*KK*2 + off));
    if constexpr (BN == 128){
      gld16(&lB[buf][(w*32)*32],    (const unsigned short*)(gB + off));
      gld16(&lB[buf][(w*32+16)*32], (const unsigned short*)(gB + (size_t)16*KK*2 + off));
    } else {
      gld16(&lB[buf][(w*16)*32],    (const unsigned short*)(gB + off));
    }
  };
  auto compute = [&](int buf){
    union { uint4 u; s8v v; } af[4], bfr[NI];
    #pragma unroll
    for (int mi=0;mi<4;++mi) af[mi].u  = *(const uint4*)&lA[buf][(wm*64+mi*16+lr)*32 + kq*8];
    #pragma unroll
    for (int ni=0;ni<NI;++ni) bfr[ni].u = *(const uint4*)&lB[buf][(wn*WNT+ni*16+lr)*32 + kq*8];
    #pragma unroll
    for (int mi=0;mi<4;++mi)
      #pragma unroll
      for (int ni=0;ni<NI;++ni)
        acc[mi][ni] = __builtin_amdgcn_mfma_f32_16x16x32_bf16(af[mi].v, bfr[ni].v, acc[mi][ni], 0,0,0);
  };

  stage(0, 0);
  __syncthreads();
  #pragma unroll
  for (int kt=1; kt<16; ++kt){
    stage(kt&1, kt);
    compute((kt&1)^1);
    __syncthreads();
  }
  compute(1);

  float sc = 0.f;
  if constexpr (OUTEPI) sc = *scale_p;
  #pragma unroll
  for (int mi=0;mi<4;++mi){
    #pragma unroll
    for (int ni=0;ni<NI;++ni){
      int row = bm*128 + wm*64 + mi*16 + kq*4;   // C/D: col=lane&15, row=(lane>>4)*4+reg
      int col = bn*BN  + wn*WNT + ni*16 + lr;
      float bs = bias[col];
      f32x4 c = acc[mi][ni];
      #pragma unroll
      for (int r=0;r<4;++r){
        float val = c[r] + bs;
        size_t off = (size_t)(row+r)*NDIM + col;
        if constexpr (OUTEPI) outF[off] = hidden[off] + sc*val;
        else                  outBf[off] = f2bf(val);
      }
    }
  }
}

// ---------------------------------------------------------------- fused scan (cooperative): A (local scan, y_loc in regs) -> B (carry) -> C (fixup+reduce)
__global__ __launch_bounds__(256) void k_scan(
    const float* __restrict__ alpha,
    const unsigned short* __restrict__ vg,
    const float* __restrict__ mix,
    const float* __restrict__ h_prev,
    float* __restrict__ L, float* __restrict__ PA,
    float* __restrict__ Gc, unsigned short* __restrict__ ybf)
{
  cg::grid_group grid = cg::this_grid();
  int blk = blockIdx.x;           // b*NCH + c  (256 blocks)
  int c = blk & (NCH-1), b = blk >> 7;
  int tid = threadIdx.x;          // d0 = 2*tid
  __shared__ float sAl[CHUNK*TT];
  __shared__ float sP[NCH];
  if (tid < CHUNK*TT) sAl[tid] = alpha[(size_t)(b*SS + c*CHUNK)*TT + tid];
  __syncthreads();

  // ---- phase A: chunk-local zero-init scan; keep per-step y_loc in registers
  float g0[TT], g1[TT];
  #pragma unroll
  for (int t=0;t<TT;++t){ g0[t]=0.f; g1[t]=0.f; }
  float ylo0[CHUNK], ylo1[CHUNK];
  const unsigned short* vp = vg + (size_t)(b*SS + c*CHUNK)*NV + tid*2;
  #pragma unroll
  for (int s2=0;s2<CHUNK;++s2){
    float y0 = 0.f, y1 = 0.f;
    #pragma unroll
    for (int t=0;t<TT;++t){
      float a = sAl[s2*TT+t], om = 1.f - a;
      ushort2 vv = *(const ushort2*)(vp + (size_t)s2*NV + t*DD);
      g0[t] = a*g0[t] + om*bf2f(vv.x);
      g1[t] = a*g1[t] + om*bf2f(vv.y);
      y0 += g0[t]; y1 += g1[t];
    }
    ylo0[s2] = y0; ylo1[s2] = y1;
  }
  #pragma unroll
  for (int t=0;t<TT;++t){
    float2 o; o.x = g0[t]; o.y = g1[t];
    *(float2*)(L + ((size_t)(b*TT+t)*NCH + c)*DD + tid*2) = o;
  }
  if (tid < TT){
    float pa = 1.f;
    #pragma unroll
    for (int s2=0;s2<CHUNK;++s2) pa *= sAl[s2*TT+tid];
    PA[(size_t)(b*TT+tid)*NCH + c] = pa;
  }
  __threadfence();
  grid.sync();

  // ---- phase B: sequential carry over chunks; blocks 0..19 (bt = blk>>1, d-half = blk&1)
  if (blk < 2*BB*TT){
    int bt = blk >> 1;
    int t = bt % TT, b2 = bt / TT;
    int d = (blk & 1)*256 + tid;
    if (tid < NCH) sP[tid] = PA[(size_t)bt*NCH + tid];
    __syncthreads();
    float carry = 0.f;
    #pragma unroll
    for (int p=0;p<PP;++p)
      carry += mix[p*TT+t] * h_prev[((size_t)(b2*PP+p)*TT + t)*DD + d];
    const float* Lp = L  + (size_t)bt*NCH*DD + d;
    float*       gc = Gc + (size_t)bt*NCH*DD + d;
    float buf[8], nbuf[8];
    #pragma unroll
    for (int j=0;j<8;++j) buf[j] = Lp[(size_t)j*DD];
    for (int c0=0;c0<NCH;c0+=8){
      if (c0+8 < NCH){
        #pragma unroll
        for (int j=0;j<8;++j) nbuf[j] = Lp[(size_t)(c0+8+j)*DD];
      }
      #pragma unroll
      for (int j=0;j<8;++j){
        gc[(size_t)(c0+j)*DD] = carry;
        carry = sP[c0+j]*carry + buf[j];
      }
      #pragma unroll
      for (int j=0;j<8;++j) buf[j] = nbuf[j];
    }
    __threadfence();
  }
  grid.sync();

  // ---- phase C: y(s) = y_loc(s) + sum_t pref_t(s) * carry_t(chunk)
  float ca0[TT], ca1[TT], pr[TT];
  #pragma unroll
  for (int t=0;t<TT;++t){
    float2 cv = *(const float2*)(Gc + ((size_t)(b*TT+t)*NCH + c)*DD + tid*2);
    ca0[t] = cv.x; ca1[t] = cv.y; pr[t] = 1.f;
  }
  unsigned short* yp = ybf + (size_t)(b*SS + c*CHUNK)*DD + tid*2;
  #pragma unroll
  for (int s2=0;s2<CHUNK;++s2){
    float y0 = ylo0[s2], y1 = ylo1[s2];
    #pragma unroll
    for (int t=0;t<TT;++t){
      pr[t] *= sAl[s2*TT+t];
      y0 += pr[t]*ca0[t];
      y1 += pr[t]*ca1[t];
    }
    ushort2 o; o.x = f2bf(y0); o.y = f2bf(y1);
    *(ushort2*)(yp + (size_t)s2*DD) = o;
  }
}

// ----------------------------------------------------------------
extern "C" void kernel_launch(void* const* d_in, const int* in_sizes, int n_in,
                              void* d_out, int out_size, void* d_ws, size_t ws_size,
                              hipStream_t stream)
{
  (void)in_sizes; (void)n_in; (void)out_size; (void)ws_size;
  const float* hs     = (const float*)d_in[0];
  const float* gamma  = (const float*)d_in[1];
  const float* beta   = (const float*)d_in[2];
  const float* W_in   = (const float*)d_in[3];
  const float* b_in   = (const float*)d_in[4];
  const float* W1     = (const float*)d_in[5];
  const float* b1     = (const float*)d_in[6];
  const float* W2     = (const float*)d_in[7];
  const float* b2     = (const float*)d_in[8];
  const float* ltau   = (const float*)d_in[9];
  const float* mix    = (const float*)d_in[10];
  const float* W_out  = (const float*)d_in[11];
  const float* b_out  = (const float*)d_in[12];
  const float* scale  = (const float*)d_in[13];
  const float* h_prev = (const float*)d_in[14];
  float* out = (float*)d_out;

  uint8_t* w = (uint8_t*)d_ws;
  unsigned short* xn   = (unsigned short*)(w);                  //  4,194,304
  unsigned short* WvT  = (unsigned short*)(w + 4194304);        //  2,621,440
  unsigned short* WoT  = (unsigned short*)(w + 6815744);        //    524,288
  float* alphaB        = (float*)(w + 7340032);                 //     81,920
  float* b_v           = (float*)(w + 7421952);                 //     10,240
  float* PA            = (float*)(w + 7432192);                 //      5,120
  float* L             = (float*)(w + 7437312);                 //  2,621,440
  float* Gc            = (float*)(w + 10058752);                //  2,621,440
  unsigned short* vg   = (unsigned short*)(w + 12680192);       // 20,971,520
  unsigned short* ybf  = (unsigned short*)(w + 33651712);       //  4,194,304
  unsigned short* W1T  = ybf;   // aliased: W1T dead before k_scan writes ybf

  hipLaunchKernelGGL(k_prep_ln, dim3(1296), dim3(256), 0, stream,
                     hs, gamma, beta, W_in, b_in, mix, W_out, W1,
                     xn, WvT, b_v, WoT, W1T);
  hipLaunchKernelGGL(k_gate, dim3(MM/64), dim3(256), 0, stream, xn, W1T, b1, W2, b2, ltau, alphaB);
  hipLaunchKernelGGL((k_gemm<128,NV,false>), dim3(NV/128, MM/128), dim3(256), 0, stream,
                     xn, WvT, b_v, nullptr, nullptr, nullptr, vg);
  {
    const float* a0 = alphaB; const unsigned short* a1 = vg;
    const float* a2 = mix; const float* a3 = h_prev;
    float* a4 = L; float* a5 = PA; float* a6 = Gc; unsigned short* a7 = ybf;
    void* args[] = { (void*)&a0, (void*)&a1, (void*)&a2, (void*)&a3,
                     (void*)&a4, (void*)&a5, (void*)&a6, (void*)&a7 };
    hipLaunchCooperativeKernel((const void*)k_scan, dim3(BB*NCH), dim3(256), args, 0, stream);
  }
  hipLaunchKernelGGL((k_gemm<64,DD,true>), dim3(DD/64, MM/128), dim3(256), 0, stream,
                     ybf, WoT, b_out, hs, scale, out, nullptr);
}

// Round 5
// 82.948 us; speedup vs baseline: 2.2279x; 2.2279x over previous
//
#include <hip/hip_runtime.h>
#include <hip/hip_bf16.h>
#include <stdint.h>

#define BB 2
#define SS 2048
#define DD 512
#define PP 13
#define TT 5
#define MH 64
#define MM (BB*SS)      // 4096 rows
#define NV (TT*DD)      // 2560
#define KK 512
#define CHUNK 16
#define NCH (SS/CHUNK)  // 128

typedef __attribute__((ext_vector_type(4))) float f32x4;
typedef __attribute__((ext_vector_type(8))) short s8v;
typedef unsigned int u32;
typedef __attribute__((address_space(3))) u32 lds_u32_t;
typedef __attribute__((address_space(1))) const u32 glb_u32_t;

__device__ __forceinline__ float bf2f(unsigned short u){
  union { unsigned int i; float f; } c; c.i = ((unsigned int)u) << 16; return c.f;
}
__device__ __forceinline__ unsigned short f2bf(float f){
  union { float f; unsigned int i; } c; c.f = f;
  unsigned int x = c.i;
  unsigned int r = (x + 0x7fffu + ((x >> 16) & 1u)) >> 16;
  return (unsigned short)r;
}
// async global->LDS, 16B per lane; LDS dest is wave-uniform base + lane*16
__device__ __forceinline__ void gld16(unsigned short* l, const unsigned short* g){
  __builtin_amdgcn_global_load_lds((glb_u32_t*)g, (lds_u32_t*)l, 16, 0, 0);
}

// ---------------------------------------------------------------- merged LN + weight-prep
// blocks [0,1024): LayerNorm, 4 rows each
// blocks [1024,1152): W_vT = mix-contracted W_in (transposed bf16) + b_v
// blocks [1152,1280): W_outT bf16
// blocks [1280,1296): W1T bf16
__global__ __launch_bounds__(256) void k_prep_ln(
    const float* __restrict__ hs,
    const float* __restrict__ gamma, const float* __restrict__ beta,
    const float* __restrict__ W_in, const float* __restrict__ b_in,
    const float* __restrict__ mix,  const float* __restrict__ W_out,
    const float* __restrict__ W1,
    unsigned short* __restrict__ xn_bf,
    unsigned short* __restrict__ W_vT, float* __restrict__ b_v,
    unsigned short* __restrict__ W_outT, unsigned short* __restrict__ W1T)
{
  int blk = blockIdx.x;
  if (blk < 1024){
    int tid = threadIdx.x;
    int lane = tid & 63;
    int row = blk*4 + (tid>>6);
    const float* x = hs + (size_t)row*DD + lane*8;
    float4 v0 = *(const float4*)x;
    float4 v1 = *(const float4*)(x+4);
    float s  = v0.x+v0.y+v0.z+v0.w + v1.x+v1.y+v1.z+v1.w;
    float sq = v0.x*v0.x+v0.y*v0.y+v0.z*v0.z+v0.w*v0.w
             + v1.x*v1.x+v1.y*v1.y+v1.z*v1.z+v1.w*v1.w;
    #pragma unroll
    for (int o=32;o>0;o>>=1){ s += __shfl_xor(s,o); sq += __shfl_xor(sq,o); }
    float mu   = s  * (1.f/DD);
    float var  = sq * (1.f/DD) - mu*mu;
    float rstd = rsqrtf(var + 1e-5f);
    float4 g0 = *(const float4*)(gamma + lane*8);
    float4 g1 = *(const float4*)(gamma + lane*8 + 4);
    float4 b0 = *(const float4*)(beta  + lane*8);
    float4 b1 = *(const float4*)(beta  + lane*8 + 4);
    union { unsigned short us[8]; uint4 u; } pk;
    pk.us[0] = f2bf((v0.x-mu)*rstd*g0.x + b0.x);
    pk.us[1] = f2bf((v0.y-mu)*rstd*g0.y + b0.y);
    pk.us[2] = f2bf((v0.z-mu)*rstd*g0.z + b0.z);
    pk.us[3] = f2bf((v0.w-mu)*rstd*g0.w + b0.w);
    pk.us[4] = f2bf((v1.x-mu)*rstd*g1.x + b1.x);
    pk.us[5] = f2bf((v1.y-mu)*rstd*g1.y + b1.y);
    pk.us[6] = f2bf((v1.z-mu)*rstd*g1.z + b1.z);
    pk.us[7] = f2bf((v1.w-mu)*rstd*g1.w + b1.w);
    *(uint4*)(xn_bf + (size_t)row*DD + lane*8) = pk.u;
  } else if (blk < 1152){
    int idx = (blk-1024) * 256 + threadIdx.x;   // 32768 total
    int d  = idx & (DD-1);
    int k0 = idx >> 9;                   // 0..63 (8 k's each)
    float mx[PP][TT];
    #pragma unroll
    for (int p=0;p<PP;++p)
      #pragma unroll
      for (int t=0;t<TT;++t) mx[p][t] = mix[p*TT+t];
    float acc[TT][8];
    #pragma unroll
    for (int t=0;t<TT;++t)
      #pragma unroll
      for (int j=0;j<8;++j) acc[t][j] = 0.f;
    #pragma unroll
    for (int j=0;j<8;++j){
      int k = k0*8 + j;
      const float* wrow = W_in + (size_t)k * (PP*DD) + d;
      #pragma unroll
      for (int p=0;p<PP;++p){
        float w = wrow[p*DD];
        #pragma unroll
        for (int t=0;t<TT;++t) acc[t][j] += mx[p][t]*w;
      }
    }
    #pragma unroll
    for (int t=0;t<TT;++t){
      union { unsigned short us[8]; uint4 u; } pk;
      #pragma unroll
      for (int j=0;j<8;++j) pk.us[j] = f2bf(acc[t][j]);
      *(uint4*)(W_vT + ((size_t)(t*DD+d))*KK + k0*8) = pk.u;
    }
    if (k0 == 0){
      #pragma unroll
      for (int t=0;t<TT;++t){
        float s = 0.f;
        #pragma unroll
        for (int p=0;p<PP;++p) s += mx[p][t]*b_in[p*DD+d];
        b_v[t*DD+d] = s;
      }
    }
  } else if (blk < 1280){
    int idx = (blk-1152)*256 + threadIdx.x; // 32768
    int n  = idx & (DD-1);
    int k0 = idx >> 9;
    union { unsigned short us[8]; uint4 u; } pk;
    #pragma unroll
    for (int j=0;j<8;++j) pk.us[j] = f2bf(W_out[(size_t)(k0*8+j)*DD + n]);
    *(uint4*)(W_outT + (size_t)n*KK + k0*8) = pk.u;
  } else {
    int idx = (blk-1280)*256 + threadIdx.x; // 4096
    int n  = idx >> 6;       // 0..63
    int k0 = idx & 63;       // 8 k's each
    union { unsigned short us[8]; uint4 u; } pk;
    #pragma unroll
    for (int j=0;j<8;++j) pk.us[j] = f2bf(W1[(size_t)(k0*8+j)*MH + n]);
    *(uint4*)(W1T + (size_t)n*KK + k0*8) = pk.u;
  }
}

// ---------------------------------------------------------------- gate: z1=tanh(xn@W1), z2=z1@W2+b2, alpha=exp(-sigmoid(z2)/tau)
__global__ __launch_bounds__(256) void k_gate(
    const unsigned short* __restrict__ xn,
    const unsigned short* __restrict__ W1T,
    const float* __restrict__ b1, const float* __restrict__ W2,
    const float* __restrict__ b2, const float* __restrict__ ltau,
    float* __restrict__ alpha)
{
  __shared__ unsigned short lA[2][64*32];
  __shared__ unsigned short lB[2][64*32];
  int bm = blockIdx.x;
  int tid = threadIdx.x, lane = tid & 63, w = tid >> 6;
  int lr = lane & 15, kq = lane >> 4;
  const uint8_t* gA = (const uint8_t*)(xn  + (size_t)(bm*64 + w*16 + (lane>>2))*KK) + (lane&3)*16;
  const uint8_t* gB = (const uint8_t*)(W1T + (size_t)(        w*16 + (lane>>2))*KK) + (lane&3)*16;
  f32x4 acc[4];
  #pragma unroll
  for (int ni=0;ni<4;++ni) acc[ni] = (f32x4){0.f,0.f,0.f,0.f};

  auto stage = [&](int buf, int kt){
    int off = kt*64;  // bytes
    gld16(&lA[buf][(w*16)*32], (const unsigned short*)(gA + off));
    gld16(&lB[buf][(w*16)*32], (const unsigned short*)(gB + off));
  };
  auto compute = [&](int buf){
    union { uint4 u; s8v v; } af, bfr[4];
    af.u = *(const uint4*)&lA[buf][(w*16+lr)*32 + kq*8];
    #pragma unroll
    for (int ni=0;ni<4;++ni) bfr[ni].u = *(const uint4*)&lB[buf][(ni*16+lr)*32 + kq*8];
    #pragma unroll
    for (int ni=0;ni<4;++ni)
      acc[ni] = __builtin_amdgcn_mfma_f32_16x16x32_bf16(af.v, bfr[ni].v, acc[ni], 0,0,0);
  };

  stage(0, 0);
  __syncthreads();
  #pragma unroll
  for (int kt=1; kt<16; ++kt){
    stage(kt&1, kt);
    compute((kt&1)^1);
    __syncthreads();
  }
  compute(1);

  float z1[4][4];
  #pragma unroll
  for (int ni=0;ni<4;++ni){
    float bb = b1[ni*16+lr];
    #pragma unroll
    for (int r=0;r<4;++r) z1[r][ni] = tanhf(acc[ni][r] + bb);
  }
  float et[TT];
  #pragma unroll
  for (int t=0;t<TT;++t) et[t] = expf(-ltau[t]);
  float a[4][TT];
  #pragma unroll
  for (int t=0;t<TT;++t){
    float w2[4];
    #pragma unroll
    for (int ni=0;ni<4;++ni) w2[ni] = W2[(ni*16+lr)*TT + t];
    #pragma unroll
    for (int r=0;r<4;++r){
      float p = z1[r][0]*w2[0] + z1[r][1]*w2[1] + z1[r][2]*w2[2] + z1[r][3]*w2[3];
      #pragma unroll
      for (int o=8;o>0;o>>=1) p += __shfl_xor(p, o);
      float z2 = p + b2[t];
      float gate = 1.f/(1.f + expf(-z2));
      a[r][t] = expf(-gate * et[t]);
    }
  }
  if (lr < TT){
    int t = lr;
    #pragma unroll
    for (int r=0;r<4;++r){
      int row = bm*64 + w*16 + kq*4 + r;
      alpha[(size_t)row*TT + t] = a[r][t];
    }
  }
}

// ---------------------------------------------------------------- bf16 MFMA GEMM, 2-phase dbuf: C = A(M,K)*Bt(N,K)^T (+bias)[+epilogue]
template<int BN, int NDIM, bool OUTEPI>
__global__ __launch_bounds__(256) void k_gemm(
    const unsigned short* __restrict__ A,
    const unsigned short* __restrict__ Bt,
    const float* __restrict__ bias,
    const float* __restrict__ hidden,
    const float* __restrict__ scale_p,
    float* __restrict__ outF,
    unsigned short* __restrict__ outBf)
{
  constexpr int NI  = (BN == 128) ? 4 : 2;
  constexpr int WNT = BN / 2;
  __shared__ unsigned short lA[2][128*32];
  __shared__ unsigned short lB[2][BN*32];
  int bn = blockIdx.x, bm = blockIdx.y;
  int tid  = threadIdx.x;
  int lane = tid & 63;
  int w    = tid >> 6;
  int wm = w >> 1, wn = w & 1;
  f32x4 acc[4][NI];
  #pragma unroll
  for (int i=0;i<4;++i)
    #pragma unroll
    for (int j=0;j<NI;++j) acc[i][j] = (f32x4){0.f,0.f,0.f,0.f};

  const uint8_t* gA = (const uint8_t*)(A + (size_t)(bm*128 + w*32 + (lane>>2))*KK) + (lane&3)*16;
  const uint8_t* gB;
  if constexpr (BN == 128) gB = (const uint8_t*)(Bt + (size_t)(bn*BN + w*32 + (lane>>2))*KK) + (lane&3)*16;
  else                     gB = (const uint8_t*)(Bt + (size_t)(bn*BN + w*16 + (lane>>2))*KK) + (lane&3)*16;
  int lr = lane & 15, kq = lane >> 4;

  auto stage = [&](int buf, int kt){
    int off = kt*64;  // bytes
    gld16(&lA[buf][(w*32)*32],    (const unsigned short*)(gA + off));
    gld16(&lA[buf][(w*32+16)*32], (const unsigned short*)(gA + (size_t)16*KK*2 + off));
    if constexpr (BN == 128){
      gld16(&lB[buf][(w*32)*32],    (const unsigned short*)(gB + off));
      gld16(&lB[buf][(w*32+16)*32], (const unsigned short*)(gB + (size_t)16*KK*2 + off));
    } else {
      gld16(&lB[buf][(w*16)*32],    (const unsigned short*)(gB + off));
    }
  };
  auto compute = [&](int buf){
    union { uint4 u; s8v v; } af[4], bfr[NI];
    #pragma unroll
    for (int mi=0;mi<4;++mi) af[mi].u  = *(const uint4*)&lA[buf][(wm*64+mi*16+lr)*32 + kq*8];
    #pragma unroll
    for (int ni=0;ni<NI;++ni) bfr[ni].u = *(const uint4*)&lB[buf][(wn*WNT+ni*16+lr)*32 + kq*8];
    #pragma unroll
    for (int mi=0;mi<4;++mi)
      #pragma unroll
      for (int ni=0;ni<NI;++ni)
        acc[mi][ni] = __builtin_amdgcn_mfma_f32_16x16x32_bf16(af[mi].v, bfr[ni].v, acc[mi][ni], 0,0,0);
  };

  stage(0, 0);
  __syncthreads();
  #pragma unroll
  for (int kt=1; kt<16; ++kt){
    stage(kt&1, kt);
    compute((kt&1)^1);
    __syncthreads();
  }
  compute(1);

  float sc = 0.f;
  if constexpr (OUTEPI) sc = *scale_p;
  #pragma unroll
  for (int mi=0;mi<4;++mi){
    #pragma unroll
    for (int ni=0;ni<NI;++ni){
      int row = bm*128 + wm*64 + mi*16 + kq*4;   // C/D: col=lane&15, row=(lane>>4)*4+reg
      int col = bn*BN  + wn*WNT + ni*16 + lr;
      float bs = bias[col];
      f32x4 c = acc[mi][ni];
      #pragma unroll
      for (int r=0;r<4;++r){
        float val = c[r] + bs;
        size_t off = (size_t)(row+r)*NDIM + col;
        if constexpr (OUTEPI) outF[off] = hidden[off] + sc*val;
        else                  outBf[off] = f2bf(val);
      }
    }
  }
}

// ---------------------------------------------------------------- scan phase A: block=(b,chunk), wave per t, lane owns 8 d.
// Load all 16 steps to regs (16B each), scan in-register, store g_loc in place + L + PA.
__global__ __launch_bounds__(320) void k_scan_a(
    const float* __restrict__ alpha,
    unsigned short* __restrict__ vg,   // in: v, out: g_loc (in place)
    float* __restrict__ L, float* __restrict__ PA)
{
  int blk = blockIdx.x;           // b*NCH + c
  int c = blk & (NCH-1), b = blk >> 7;
  int tid = threadIdx.x;          // 320 = 5 waves
  int t  = tid >> 6;              // wave = t
  int d8 = tid & 63;              // 8 consecutive d
  __shared__ float sAl[CHUNK*TT];
  if (tid < CHUNK*TT) sAl[tid] = alpha[(size_t)(b*SS + c*CHUNK)*TT + tid];
  __syncthreads();
  unsigned short* vp = vg + (size_t)(b*SS + c*CHUNK)*NV + t*DD + d8*8;
  uint4 vv[CHUNK];
  #pragma unroll
  for (int s2=0;s2<CHUNK;++s2) vv[s2] = *(const uint4*)(vp + (size_t)s2*NV);
  float g[8];
  #pragma unroll
  for (int j=0;j<8;++j) g[j] = 0.f;
  float pa = 1.f;
  #pragma unroll
  for (int s2=0;s2<CHUNK;++s2){
    float a = sAl[s2*TT+t], om = 1.f - a;
    const unsigned short* pv = (const unsigned short*)&vv[s2];
    union { unsigned short us[8]; uint4 u; } o;
    #pragma unroll
    for (int j=0;j<8;++j){ g[j] = a*g[j] + om*bf2f(pv[j]); o.us[j] = f2bf(g[j]); }
    *(uint4*)(vp + (size_t)s2*NV) = o.u;
    pa *= a;
  }
  float* Lp = L + ((size_t)(b*TT+t)*NCH + c)*DD + d8*8;
  *(float4*)Lp     = (float4){g[0],g[1],g[2],g[3]};
  *(float4*)(Lp+4) = (float4){g[4],g[5],g[6],g[7]};
  if (d8 == 0) PA[(size_t)(b*TT+t)*NCH + c] = pa;
}

// ---------------------------------------------------------------- scan phase B: sequential carry over chunks (one block per (b,t))
__global__ __launch_bounds__(512) void k_scan_b(
    const float* __restrict__ mix,
    const float* __restrict__ h_prev,
    const float* __restrict__ PA,
    const float* __restrict__ L,
    float* __restrict__ Gc)
{
  int blk = blockIdx.x;      // b*TT + t  (10 blocks)
  int t = blk % TT, b = blk / TT;
  int d = threadIdx.x;       // 512
  __shared__ float sP[NCH];
  if (d < NCH) sP[d] = PA[(size_t)(b*TT+t)*NCH + d];
  __syncthreads();
  float carry = 0.f;         // g_init = sum_p mix[p,t]*h_prev[b,p,t,d]
  #pragma unroll
  for (int p=0;p<PP;++p)
    carry += mix[p*TT+t] * h_prev[((size_t)(b*PP+p)*TT + t)*DD + d];
  const float* Lp = L  + (size_t)(b*TT+t)*NCH*DD + d;
  float*       gc = Gc + (size_t)(b*TT+t)*NCH*DD + d;
  float buf[8], nbuf[8];
  #pragma unroll
  for (int j=0;j<8;++j) buf[j] = Lp[(size_t)j*DD];
  for (int c0=0;c0<NCH;c0+=8){
    if (c0+8 < NCH){
      #pragma unroll
      for (int j=0;j<8;++j) nbuf[j] = Lp[(size_t)(c0+8+j)*DD];
    }
    #pragma unroll
    for (int j=0;j<8;++j){
      gc[(size_t)(c0+j)*DD] = carry;
      carry = sP[c0+j]*carry + buf[j];
    }
    #pragma unroll
    for (int j=0;j<8;++j) buf[j] = nbuf[j];
  }
}

// ---------------------------------------------------------------- scan phase C: block=(b,chunk), wave owns 4 steps, lane owns 8 d.
// y(s) = sum_t [ g_loc_t(s) + pref_t(s)*carry_t ]; no recurrence -> step-parallel.
__global__ __launch_bounds__(256) void k_scan_c(
    const float* __restrict__ alpha,
    const unsigned short* __restrict__ g_loc,
    const float* __restrict__ Gc,
    unsigned short* __restrict__ ybf)
{
  int blk = blockIdx.x;           // b*NCH + c
  int c = blk & (NCH-1), b = blk >> 7;
  int tid = threadIdx.x;          // 256 = 4 waves
  int s4 = tid >> 6;              // wave covers steps s4*4 .. s4*4+3
  int d8 = tid & 63;
  __shared__ float sAl[CHUNK*TT];
  if (tid < CHUNK*TT) sAl[tid] = alpha[(size_t)(b*SS + c*CHUNK)*TT + tid];
  __syncthreads();
  float ca[TT][8];
  #pragma unroll
  for (int t=0;t<TT;++t){
    const float* gp = Gc + ((size_t)(b*TT+t)*NCH + c)*DD + d8*8;
    float4 c0 = *(const float4*)gp;
    float4 c1 = *(const float4*)(gp+4);
    ca[t][0]=c0.x; ca[t][1]=c0.y; ca[t][2]=c0.z; ca[t][3]=c0.w;
    ca[t][4]=c1.x; ca[t][5]=c1.y; ca[t][6]=c1.z; ca[t][7]=c1.w;
  }
  float pr[TT];
  #pragma unroll
  for (int t=0;t<TT;++t){
    float p = 1.f;
    for (int j=0;j<s4*4;++j) p *= sAl[j*TT+t];
    pr[t] = p;
  }
  const unsigned short* gl = g_loc + (size_t)(b*SS + c*CHUNK)*NV + d8*8;
  unsigned short* yp = ybf + (size_t)(b*SS + c*CHUNK)*DD + d8*8;
  #pragma unroll
  for (int i=0;i<4;++i){
    int s2 = s4*4 + i;
    float y[8];
    #pragma unroll
    for (int j=0;j<8;++j) y[j] = 0.f;
    #pragma unroll
    for (int t=0;t<TT;++t){
      pr[t] *= sAl[s2*TT+t];
      uint4 gv = *(const uint4*)(gl + (size_t)s2*NV + t*DD);
      const unsigned short* gp = (const unsigned short*)&gv;
      #pragma unroll
      for (int j=0;j<8;++j) y[j] += bf2f(gp[j]) + pr[t]*ca[t][j];
    }
    union { unsigned short us[8]; uint4 u; } o;
    #pragma unroll
    for (int j=0;j<8;++j) o.us[j] = f2bf(y[j]);
    *(uint4*)(yp + (size_t)s2*DD) = o.u;
  }
}

// ----------------------------------------------------------------
extern "C" void kernel_launch(void* const* d_in, const int* in_sizes, int n_in,
                              void* d_out, int out_size, void* d_ws, size_t ws_size,
                              hipStream_t stream)
{
  (void)in_sizes; (void)n_in; (void)out_size; (void)ws_size;
  const float* hs     = (const float*)d_in[0];
  const float* gamma  = (const float*)d_in[1];
  const float* beta   = (const float*)d_in[2];
  const float* W_in   = (const float*)d_in[3];
  const float* b_in   = (const float*)d_in[4];
  const float* W1     = (const float*)d_in[5];
  const float* b1     = (const float*)d_in[6];
  const float* W2     = (const float*)d_in[7];
  const float* b2     = (const float*)d_in[8];
  const float* ltau   = (const float*)d_in[9];
  const float* mix    = (const float*)d_in[10];
  const float* W_out  = (const float*)d_in[11];
  const float* b_out  = (const float*)d_in[12];
  const float* scale  = (const float*)d_in[13];
  const float* h_prev = (const float*)d_in[14];
  float* out = (float*)d_out;

  uint8_t* w = (uint8_t*)d_ws;
  unsigned short* xn   = (unsigned short*)(w);                  //  4,194,304
  unsigned short* WvT  = (unsigned short*)(w + 4194304);        //  2,621,440
  unsigned short* WoT  = (unsigned short*)(w + 6815744);        //    524,288
  float* alphaB        = (float*)(w + 7340032);                 //     81,920
  float* b_v           = (float*)(w + 7421952);                 //     10,240
  float* PA            = (float*)(w + 7432192);                 //      5,120
  float* L             = (float*)(w + 7437312);                 //  2,621,440
  float* Gc            = (float*)(w + 10058752);                //  2,621,440
  unsigned short* vg   = (unsigned short*)(w + 12680192);       // 20,971,520
  unsigned short* ybf  = (unsigned short*)(w + 33651712);       //  4,194,304
  unsigned short* W1T  = ybf;   // aliased: W1T dead before k_scan_c writes ybf

  hipLaunchKernelGGL(k_prep_ln, dim3(1296), dim3(256), 0, stream,
                     hs, gamma, beta, W_in, b_in, mix, W_out, W1,
                     xn, WvT, b_v, WoT, W1T);
  hipLaunchKernelGGL(k_gate, dim3(MM/64), dim3(256), 0, stream, xn, W1T, b1, W2, b2, ltau, alphaB);
  hipLaunchKernelGGL((k_gemm<128,NV,false>), dim3(NV/128, MM/128), dim3(256), 0, stream,
                     xn, WvT, b_v, nullptr, nullptr, nullptr, vg);
  hipLaunchKernelGGL(k_scan_a, dim3(BB*NCH), dim3(320), 0, stream, alphaB, vg, L, PA);
  hipLaunchKernelGGL(k_scan_b, dim3(BB*TT), dim3(512), 0, stream, mix, h_prev, PA, L, Gc);
  hipLaunchKernelGGL(k_scan_c, dim3(BB*NCH), dim3(256), 0, stream, alphaB, vg, Gc, ybf);
  hipLaunchKernelGGL((k_gemm<64,DD,true>), dim3(DD/64, MM/128), dim3(256), 0, stream,
                     ybf, WoT, b_out, hs, scale, out, nullptr);
}